// Round 15
// baseline (26.743 us; speedup 1.0000x reference)
//
#include <hip/hip_runtime.h>
#include <math.h>

#define NH    16384   // Hadamard size (2^14)
#define NRES  8192
#define NINP  64
#define BATCH 512

typedef float v2f __attribute__((ext_vector_type(2)));

// ---------------- LDS swizzle (verified r14: all layouts rank-3) -----------
__device__ __forceinline__ constexpr int gfoldc(int v) {
    return ((v >> 5) & 7) ^ ((v >> 8) & 7) ^ ((v >> 11) & 7);
}
__device__ __forceinline__ constexpr int physf(int v) { return v ^ (gfoldc(v) << 2); }

// ---------------- register butterflies -------------------------------------
template <int T>
__device__ __forceinline__ void pstage(v2f X[32]) {
#pragma unroll
    for (int p = 0; p < 32; ++p) if (!(p & T)) {
        v2f A = X[p], B = X[p | T];
        X[p]     = A + B;
        X[p | T] = A - B;
    }
}
__device__ __forceinline__ void vstage0(v2f X[32]) {
#pragma unroll
    for (int p = 0; p < 32; ++p) {
        float a = X[p].x, b = X[p].y;
        X[p].x = a + b; X[p].y = a - b;
    }
}

// ---------------- in-place lane butterflies (DPP) ---------------------------
template <int CTRL>
__device__ __forceinline__ float dppf(float v) {
    return __builtin_bit_cast(float,
        __builtin_amdgcn_update_dpp(0, __builtin_bit_cast(int, v), CTRL, 0xF, 0xF, true));
}
template <int CTRL>
__device__ __forceinline__ void dpp_bfly(v2f X[32], v2f sgn) {
#pragma unroll
    for (int p = 0; p < 32; ++p) {
        float y0 = dppf<CTRL>(X[p].x);
        float y1 = dppf<CTRL>(X[p].y);
        X[p] = sgn * X[p] + (v2f){y0, y1};
    }
}

// ---------------- permlane pair swaps ---------------------------------------
__device__ __forceinline__ void pl16_swap(float& a, float& b) {
    asm("v_permlane16_swap_b32 %0, %1" : "+v"(a), "+v"(b));
}
__device__ __forceinline__ void pl32_swap(float& a, float& b) {
    asm("v_permlane32_swap_b32 %0, %1" : "+v"(a), "+v"(b));
}
__device__ __forceinline__ void swap_j2_l4(v2f X[32]) {
#pragma unroll
    for (int p = 0; p < 32; ++p) if (!(p & 8)) {
        float a = X[p].x, b = X[p | 8].x; pl16_swap(a, b); X[p].x = a; X[p | 8].x = b;
        float c = X[p].y, d = X[p | 8].y; pl16_swap(c, d); X[p].y = c; X[p | 8].y = d;
    }
}
__device__ __forceinline__ void swap_j3_l5(v2f X[32]) {
#pragma unroll
    for (int p = 0; p < 32; ++p) if (!(p & 16)) {
        float a = X[p].x, b = X[p | 16].x; pl32_swap(a, b); X[p].x = a; X[p | 16].x = b;
        float c = X[p].y, d = X[p | 16].y; pl32_swap(c, d); X[p].y = c; X[p | 16].y = d;
    }
}

// ---------------- per-layer phases (r14 custody, verbatim) ------------------
// pre: v{0,1}; 4 j-stages; dpp lane bits; permlane swaps; 2 new j-stages.
__device__ __forceinline__ void phase_pre(v2f X[32], v2f s1, v2f s2) {
    vstage0(X); pstage<1>(X);
    pstage<2>(X); pstage<4>(X); pstage<8>(X); pstage<16>(X);
    dpp_bfly<0xB1>(X, s1);
    dpp_bfly<0x4E>(X, s2);
    swap_j2_l4(X); swap_j3_l5(X);
    pstage<8>(X); pstage<16>(X);
}
__device__ __forceinline__ void phase_post(v2f X[32]) {
    pstage<2>(X); pstage<4>(X); pstage<8>(X); pstage<16>(X);
}

// ---------------- LDS / global helpers --------------------------------------
#define GOFF4(g, G0, G1, G2, G3) \
    ((((g) & 1) ? (G0) : 0) | (((g) & 2) ? (G1) : 0) | \
     (((g) & 4) ? (G2) : 0) | (((g) & 8) ? (G3) : 0))

template <int G0, int G1, int G2, int G3>
__device__ __forceinline__ void wrx(float4* L, int Q, const v2f X[32]) {
#pragma unroll
    for (int g = 0; g < 16; ++g) {
        const int a = Q ^ physf(GOFF4(g, G0, G1, G2, G3));
        L[(unsigned)a >> 2] = make_float4(X[2*g].x, X[2*g].y, X[2*g+1].x, X[2*g+1].y);
    }
}
template <int G0, int G1, int G2, int G3>
__device__ __forceinline__ void rdx(const float4* L, int Q, v2f X[32]) {
#pragma unroll
    for (int g = 0; g < 16; ++g) {
        const int a = Q ^ physf(GOFF4(g, G0, G1, G2, G3));
        float4 v = L[(unsigned)a >> 2];
        X[2*g]   = (v2f){v.x, v.y};
        X[2*g+1] = (v2f){v.z, v.w};
    }
}
template <int G0, int G1, int G2, int G3>
__device__ __forceinline__ void diag_load(float4 pf[16], const float* base) {
#pragma unroll
    for (int g = 0; g < 16; ++g)
        pf[g] = *(const float4*)(base + GOFF4(g, G0, G1, G2, G3));
}
__device__ __forceinline__ void diag_apply(const float4 pf[16], v2f X[32]) {
#pragma unroll
    for (int g = 0; g < 16; ++g) {
        X[2*g]   *= (v2f){pf[g].x, pf[g].y};
        X[2*g+1] *= (v2f){pf[g].z, pf[g].w};
    }
}

// LDS-only barrier (global prefetches stay in flight)
#define BAR() asm volatile("s_waitcnt lgkmcnt(0)\n\ts_barrier" ::: "memory")

// Fast erf: erf(z) ~ tanh(z*(1.1283793 + 0.10090*z^2)), max err ~1e-3.
__device__ __forceinline__ float erf_fast(float z) {
    float p = z * z;
    float u = z * fmaf(p, 0.10090f, 1.1283793f);
    float e = __builtin_amdgcn_exp2f(u * 2.8853902f);
    float r = __builtin_amdgcn_rcpf(e + 1.0f);
    return fmaf(-2.0f, r, 1.0f);
}

// ---------------------------------------------------------------------------
// Dual-row variant of the verified r14 kernel: one block = rows 2b, 2b+1.
// Row A and row B are fully independent instruction streams in each thread;
// diag/bias registers are shared (row-independent). Custody plan identical
// to r14 (see its header comment); LDS buffers disjoint per row (128 KB).
// ---------------------------------------------------------------------------
__global__ __launch_bounds__(256, 1) void st_kernel(
    const float* __restrict__ state, const float* __restrict__ inputs,
    const float* __restrict__ bias,  const float* __restrict__ diag,
    float* __restrict__ out)
{
    __shared__ float4 lds4[2][NH / 4];    // 128 KB of the 160 KB LDS
    const int t = threadIdx.x;            // 0..255
    const int rA = blockIdx.x * 2;        // rows 2b, 2b+1
    const int rB = rA + 1;
    const int l = t & 63, w = t >> 6;
    const int l0=l&1, l1=(l>>1)&1, l2=(l>>2)&1, l3=(l>>3)&1, l4=(l>>4)&1, l5=(l>>5)&1;
    const int w0=w&1, w1=(w>>1)&1;

    const v2f s1 = (v2f){l0 ? -1.f : 1.f, l0 ? -1.f : 1.f};
    const v2f s2 = (v2f){l1 ? -1.f : 1.f, l1 ? -1.f : 1.f};

    // idx-space thread bases (r14 custody tables)
    const int b_w1 = l0*64 + l1*128 + l2*256 + l3*512 + l4*16 + l5*32
                   + w0*4096 + w1*8192;
    const int b_r1 = l0*4 + l1*8 + l2*64 + l3*128 + l4*16 + l5*32
                   + w0*1024 + w1*2048;
    const int b_w2 = l0*4 + l1*8 + l2*64 + l3*128 + l4*4096 + l5*8192
                   + w0*1024 + w1*2048;
    const int b_r2 = l0*4 + l1*8 + l2*256 + l3*512 + l4*16 + l5*32
                   + w0*4096 + w1*8192;
    const int b_w3 = l0*4 + l1*8 + l2*256 + l3*512 + l4*1024 + l5*2048
                   + w0*4096 + w1*8192;

    v2f XA[32], XB[32];
    float4 pf[16];

    // ---------- prologue: both rows + shared diag0 (idx = t*64 + f) ---------
    if (t < 128) {
        const float* sA = state + (size_t)rA * NRES + t * 64;
        const float* sB = state + (size_t)rB * NRES + t * 64;
        const float* d0 = diag + t * 64;
#pragma unroll
        for (int g = 0; g < 16; ++g) {
            float4 a = *(const float4*)(sA + 4 * g);
            float4 b = *(const float4*)(sB + 4 * g);
            float4 d = *(const float4*)(d0 + 4 * g);
            XA[2*g]   = (v2f){0.9f * a.x * d.x, 0.9f * a.y * d.y};
            XA[2*g+1] = (v2f){0.9f * a.z * d.z, 0.9f * a.w * d.w};
            XB[2*g]   = (v2f){0.9f * b.x * d.x, 0.9f * b.y * d.y};
            XB[2*g+1] = (v2f){0.9f * b.z * d.z, 0.9f * b.w * d.w};
        }
    } else if (t == 128) {
        const float* iA = inputs + rA * NINP;
        const float* iB = inputs + rB * NINP;
        const float* d0 = diag + NRES;
#pragma unroll
        for (int g = 0; g < 16; ++g) {
            float4 a = *(const float4*)(iA + 4 * g);
            float4 b = *(const float4*)(iB + 4 * g);
            float4 d = *(const float4*)(d0 + 4 * g);
            XA[2*g]   = (v2f){0.4f * a.x * d.x, 0.4f * a.y * d.y};
            XA[2*g+1] = (v2f){0.4f * a.z * d.z, 0.4f * a.w * d.w};
            XB[2*g]   = (v2f){0.4f * b.x * d.x, 0.4f * b.y * d.y};
            XB[2*g+1] = (v2f){0.4f * b.z * d.z, 0.4f * b.w * d.w};
        }
    } else {
#pragma unroll
        for (int p = 0; p < 32; ++p) { XA[p] = (v2f){0.f, 0.f}; XB[p] = (v2f){0.f, 0.f}; }
    }

    // ================= layer 0 =================
    phase_pre(XA, s1, s2);
    phase_pre(XB, s1, s2);

    // diag1 prefetch (EX1-R custody, shared between rows)
    diag_load<256, 512, 4096, 8192>(pf, diag + NH + b_r1);

    // EX1
    {
        const int Qw = physf(b_w1), Qr = physf(b_r1);
        wrx<4, 8, 1024, 2048>(lds4[0], Qw, XA);
        wrx<4, 8, 1024, 2048>(lds4[1], Qw, XB);
        BAR();
        rdx<256, 512, 4096, 8192>(lds4[0], Qr, XA);
        rdx<256, 512, 4096, 8192>(lds4[1], Qr, XB);
    }
    phase_post(XA);
    phase_post(XB);

    // ================= layer 1 =================
    diag_apply(pf, XA);
    diag_apply(pf, XB);
    phase_pre(XA, s1, s2);
    phase_pre(XB, s1, s2);

    // diag2 prefetch (EX2-R custody, shared)
    diag_load<64, 128, 1024, 2048>(pf, diag + 2 * NH + b_r2);

    // EX2
    BAR();                                    // protect EX1 reads
    {
        const int Qw = physf(b_w2), Qr = physf(b_r2);
        wrx<256, 512, 16, 32>(lds4[0], Qw, XA);
        wrx<256, 512, 16, 32>(lds4[1], Qw, XB);
        BAR();
        rdx<64, 128, 1024, 2048>(lds4[0], Qr, XA);
        rdx<64, 128, 1024, 2048>(lds4[1], Qr, XB);
    }
    phase_post(XA);
    phase_post(XB);

    // ================= layer 2 =================
    diag_apply(pf, XA);
    diag_apply(pf, XB);
    phase_pre(XA, s1, s2);
    phase_pre(XB, s1, s2);

    // bias prefetch (store custody = EX1-R layout, shared)
    float4 bv[8];
#pragma unroll
    for (int g = 0; g < 8; ++g)
        bv[g] = *(const float4*)(bias + b_r1 + GOFF4(g, 256, 512, 4096, 0));

    // EX3
    BAR();                                    // protect EX2 reads
    {
        const int Qw = physf(b_w3), Qr = physf(b_r1);
        wrx<64, 128, 16, 32>(lds4[0], Qw, XA);
        wrx<64, 128, 16, 32>(lds4[1], Qw, XB);
        BAR();
        rdx<256, 512, 4096, 8192>(lds4[0], Qr, XA);
        rdx<256, 512, 4096, 8192>(lds4[1], Qr, XB);
    }
    phase_post(XA);
    phase_post(XB);

    // ---------- epilogue: idx13 = j3 -> packs with bit4=0 (g<8), both rows --
    {
        float* oA = out + (size_t)rA * NRES;
        float* oB = out + (size_t)rB * NRES;
        const float inv = 1.0f / (float)NH;
#pragma unroll
        for (int g = 0; g < 8; ++g) {
            const int a = b_r1 + GOFF4(g, 256, 512, 4096, 0);
            float4 oa, ob;
            oa.x = erf_fast(fmaf(XA[2*g].x,   inv, bv[g].x));
            oa.y = erf_fast(fmaf(XA[2*g].y,   inv, bv[g].y));
            oa.z = erf_fast(fmaf(XA[2*g+1].x, inv, bv[g].z));
            oa.w = erf_fast(fmaf(XA[2*g+1].y, inv, bv[g].w));
            ob.x = erf_fast(fmaf(XB[2*g].x,   inv, bv[g].x));
            ob.y = erf_fast(fmaf(XB[2*g].y,   inv, bv[g].y));
            ob.z = erf_fast(fmaf(XB[2*g+1].x, inv, bv[g].z));
            ob.w = erf_fast(fmaf(XB[2*g+1].y, inv, bv[g].w));
            *(float4*)(oA + a) = oa;
            *(float4*)(oB + a) = ob;
        }
    }
}

extern "C" void kernel_launch(void* const* d_in, const int* in_sizes, int n_in,
                              void* d_out, int out_size, void* d_ws, size_t ws_size,
                              hipStream_t stream) {
    (void)in_sizes; (void)n_in; (void)out_size; (void)d_ws; (void)ws_size;
    const float* state  = (const float*)d_in[0];
    const float* inputs = (const float*)d_in[1];
    const float* bias   = (const float*)d_in[2];
    const float* diag   = (const float*)d_in[3];
    float* out = (float*)d_out;

    hipLaunchKernelGGL(st_kernel, dim3(BATCH / 2), dim3(256), 0, stream,
                       state, inputs, bias, diag, out);
}

// Round 16
// 23.808 us; speedup vs baseline: 1.1233x; 1.1233x over previous
//
#include <hip/hip_runtime.h>
#include <math.h>

#define NH    16384   // Hadamard size (2^14)
#define NRES  8192
#define NINP  64
#define BATCH 512

typedef float v2f __attribute__((ext_vector_type(2)));

// ---------------- LDS swizzle ----------------------------------------------
// phys = idx ^ (gfold<<2), gfold = idx[5:7]^idx[8:10]^idx[11:13]. Bijective,
// float4-aligned. All 6 exchange layouts verified rank-3 lane->quadbank
// (conflict-free b128).
__device__ __forceinline__ constexpr int gfoldc(int v) {
    return ((v >> 5) & 7) ^ ((v >> 8) & 7) ^ ((v >> 11) & 7);
}
__device__ __forceinline__ constexpr int physf(int v) { return v ^ (gfoldc(v) << 2); }

// ---------------- register butterflies (compiler packs v2f) ----------------
template <int T>
__device__ __forceinline__ void pstage(v2f X[32]) {
#pragma unroll
    for (int p = 0; p < 32; ++p) if (!(p & T)) {
        v2f A = X[p], B = X[p | T];
        X[p]     = A + B;
        X[p | T] = A - B;
    }
}
__device__ __forceinline__ void vstage0(v2f X[32]) {
#pragma unroll
    for (int p = 0; p < 32; ++p) {
        float a = X[p].x, b = X[p].y;
        X[p].x = a + b; X[p].y = a - b;
    }
}

// ---------------- in-place lane butterflies (DPP) ---------------------------
template <int CTRL>
__device__ __forceinline__ float dppf(float v) {
    return __builtin_bit_cast(float,
        __builtin_amdgcn_update_dpp(0, __builtin_bit_cast(int, v), CTRL, 0xF, 0xF, true));
}
// x' = sgn*x + x[lane^k]; sgn = (lane&k) ? -1 : +1.
template <int CTRL>
__device__ __forceinline__ void dpp_bfly(v2f X[32], v2f sgn) {
#pragma unroll
    for (int p = 0; p < 32; ++p) {
        float y0 = dppf<CTRL>(X[p].x);
        float y1 = dppf<CTRL>(X[p].y);
        X[p] = sgn * X[p] + (v2f){y0, y1};
    }
}

// ---------------- permlane pair swaps (1 instr per reg-pair) ----------------
__device__ __forceinline__ void pl16_swap(float& a, float& b) {
    asm("v_permlane16_swap_b32 %0, %1" : "+v"(a), "+v"(b));
}
__device__ __forceinline__ void pl32_swap(float& a, float& b) {
    asm("v_permlane32_swap_b32 %0, %1" : "+v"(a), "+v"(b));
}
// swap custody of pack-bit3 (pairs p,p|8) with lane-bit4
__device__ __forceinline__ void swap_j2_l4(v2f X[32]) {
#pragma unroll
    for (int p = 0; p < 32; ++p) if (!(p & 8)) {
        float a = X[p].x, b = X[p | 8].x; pl16_swap(a, b); X[p].x = a; X[p | 8].x = b;
        float c = X[p].y, d = X[p | 8].y; pl16_swap(c, d); X[p].y = c; X[p | 8].y = d;
    }
}
// swap custody of pack-bit4 (pairs p,p|16) with lane-bit5
__device__ __forceinline__ void swap_j3_l5(v2f X[32]) {
#pragma unroll
    for (int p = 0; p < 32; ++p) if (!(p & 16)) {
        float a = X[p].x, b = X[p | 16].x; pl32_swap(a, b); X[p].x = a; X[p | 16].x = b;
        float c = X[p].y, d = X[p | 16].y; pl32_swap(c, d); X[p].y = c; X[p | 16].y = d;
    }
}

// ---------------- LDS / global helpers --------------------------------------
#define GOFF4(g, G0, G1, G2, G3) \
    ((((g) & 1) ? (G0) : 0) | (((g) & 2) ? (G1) : 0) | \
     (((g) & 4) ? (G2) : 0) | (((g) & 8) ? (G3) : 0))

#define WRX(Q, G0, G1, G2, G3) do { _Pragma("unroll") \
    for (int g = 0; g < 16; ++g) { \
        const int a = (Q) ^ physf(GOFF4(g, G0, G1, G2, G3)); \
        lds4[(unsigned)a >> 2] = \
            make_float4(X[2*g].x, X[2*g].y, X[2*g+1].x, X[2*g+1].y); \
    } } while (0)

#define RDX(Q, G0, G1, G2, G3) do { _Pragma("unroll") \
    for (int g = 0; g < 16; ++g) { \
        const int a = (Q) ^ physf(GOFF4(g, G0, G1, G2, G3)); \
        float4 v = lds4[(unsigned)a >> 2]; \
        X[2*g]   = (v2f){v.x, v.y}; \
        X[2*g+1] = (v2f){v.z, v.w}; \
    } } while (0)

#define DIAG_LOAD(PF, BASE, G0, G1, G2, G3) do { _Pragma("unroll") \
    for (int g = 0; g < 16; ++g) \
        (PF)[g] = *(const float4*)((BASE) + GOFF4(g, G0, G1, G2, G3)); } while (0)

#define DIAG_APPLY(PF) do { _Pragma("unroll") \
    for (int g = 0; g < 16; ++g) { \
        X[2*g]   *= (v2f){(PF)[g].x, (PF)[g].y}; \
        X[2*g+1] *= (v2f){(PF)[g].z, (PF)[g].w}; \
    } } while (0)

// LDS-only barrier (global prefetches stay in flight)
#define BAR() asm volatile("s_waitcnt lgkmcnt(0)\n\ts_barrier" ::: "memory")

// Fast erf: erf(z) ~ tanh(z*(1.1283793 + 0.10090*z^2)), max err ~1e-3.
__device__ __forceinline__ float erf_fast(float z) {
    float p = z * z;
    float u = z * fmaf(p, 0.10090f, 1.1283793f);
    float e = __builtin_amdgcn_exp2f(u * 2.8853902f);
    float r = __builtin_amdgcn_rcpf(e + 1.0f);
    return fmaf(-2.0f, r, 1.0f);
}

// ---------------------------------------------------------------------------
// Coalesced-custody plan (256 threads, 64 floats/thread). See r14 notes:
// Load custody (natural): v{0,1} j{2,3,4,5} l{6..11} w{12,13}.
// Per layer: v; 4 j-stages; dpp(2 lane bits); permlane swaps; 2 j-stages;
// LDS relabel exchange; 4 j-stages. diag1/bias/store coalesced 1KB/instr,
// diag2 full-line 256B segments.
// ---------------------------------------------------------------------------
__global__ __launch_bounds__(256, 2) void st_kernel(
    const float* __restrict__ state, const float* __restrict__ inputs,
    const float* __restrict__ bias,  const float* __restrict__ diag,
    float* __restrict__ out)
{
    __shared__ float4 lds4[NH / 4];
    const int t = threadIdx.x;   // 0..255
    const int r = blockIdx.x;    // 0..511
    const int l = t & 63, w = t >> 6;
    const int l0=l&1, l1=(l>>1)&1, l2=(l>>2)&1, l3=(l>>3)&1, l4=(l>>4)&1, l5=(l>>5)&1;
    const int w0=w&1, w1=(w>>1)&1;

    const v2f s1 = (v2f){l0 ? -1.f : 1.f, l0 ? -1.f : 1.f};
    const v2f s2 = (v2f){l1 ? -1.f : 1.f, l1 ? -1.f : 1.f};

    // idx-space thread bases (float units) per custody tables
    const int b_w1 = l0*64 + l1*128 + l2*256 + l3*512 + l4*16 + l5*32
                   + w0*4096 + w1*8192;
    const int b_r1 = l0*4 + l1*8 + l2*64 + l3*128 + l4*16 + l5*32
                   + w0*1024 + w1*2048;
    const int b_w2 = l0*4 + l1*8 + l2*64 + l3*128 + l4*4096 + l5*8192
                   + w0*1024 + w1*2048;
    const int b_r2 = l0*4 + l1*8 + l2*256 + l3*512 + l4*16 + l5*32
                   + w0*4096 + w1*8192;
    const int b_w3 = l0*4 + l1*8 + l2*256 + l3*512 + l4*1024 + l5*2048
                   + w0*4096 + w1*8192;

    v2f X[32];
    float4 pf[16];

    // ---------- prologue: load + diag0 (natural layout idx = t*64 + f) ------
    if (t < 128) {
        const float* srow = state + (size_t)r * NRES + t * 64;
        const float* d0   = diag + t * 64;
#pragma unroll
        for (int g = 0; g < 16; ++g) {
            float4 v = *(const float4*)(srow + 4 * g);
            float4 d = *(const float4*)(d0 + 4 * g);
            X[2*g]   = (v2f){0.9f * v.x * d.x, 0.9f * v.y * d.y};
            X[2*g+1] = (v2f){0.9f * v.z * d.z, 0.9f * v.w * d.w};
        }
    } else if (t == 128) {
        const float* irow = inputs + r * NINP;
        const float* d0   = diag + NRES;
#pragma unroll
        for (int g = 0; g < 16; ++g) {
            float4 v = *(const float4*)(irow + 4 * g);
            float4 d = *(const float4*)(d0 + 4 * g);
            X[2*g]   = (v2f){0.4f * v.x * d.x, 0.4f * v.y * d.y};
            X[2*g+1] = (v2f){0.4f * v.z * d.z, 0.4f * v.w * d.w};
        }
    } else {
#pragma unroll
        for (int p = 0; p < 32; ++p) X[p] = (v2f){0.f, 0.f};
    }

    // ================= layer 0 =================
    vstage0(X); pstage<1>(X);                       // idx 0,1
    pstage<2>(X); pstage<4>(X); pstage<8>(X); pstage<16>(X);   // idx 2,3,4,5
    dpp_bfly<0xB1>(X, s1);                          // idx 6 (l0)
    dpp_bfly<0x4E>(X, s2);                          // idx 7 (l1)
    swap_j2_l4(X); swap_j3_l5(X);                   // j2<-10, j3<-11
    pstage<8>(X); pstage<16>(X);                    // idx 10, 11

    // diag1 prefetch (EX1-R custody: coalesced 1KB/instr)
    DIAG_LOAD(pf, diag + NH + b_r1, 256, 512, 4096, 8192);

    // EX1
    { const int Q = physf(b_w1); WRX(Q, 4, 8, 1024, 2048); }
    BAR();
    { const int Q = physf(b_r1); RDX(Q, 256, 512, 4096, 8192); }
    pstage<2>(X); pstage<4>(X); pstage<8>(X); pstage<16>(X);   // idx 8,9,12,13

    // ================= layer 1 =================
    DIAG_APPLY(pf);                                 // diag1
    vstage0(X); pstage<1>(X);                       // idx 0,1
    pstage<2>(X); pstage<4>(X); pstage<8>(X); pstage<16>(X);   // idx 8,9,12,13
    dpp_bfly<0xB1>(X, s1);                          // idx 2
    dpp_bfly<0x4E>(X, s2);                          // idx 3
    swap_j2_l4(X); swap_j3_l5(X);                   // j2<-4, j3<-5
    pstage<8>(X); pstage<16>(X);                    // idx 4, 5

    // diag2 prefetch (EX2-R custody: 4x256B full-line segments/instr)
    DIAG_LOAD(pf, diag + 2 * NH + b_r2, 64, 128, 1024, 2048);

    // EX2
    BAR();                                          // protect EX1 reads
    { const int Q = physf(b_w2); WRX(Q, 256, 512, 16, 32); }
    BAR();
    { const int Q = physf(b_r2); RDX(Q, 64, 128, 1024, 2048); }
    pstage<2>(X); pstage<4>(X); pstage<8>(X); pstage<16>(X);   // idx 6,7,10,11

    // ================= layer 2 =================
    DIAG_APPLY(pf);                                 // diag2
    vstage0(X); pstage<1>(X);                       // idx 0,1
    pstage<2>(X); pstage<4>(X); pstage<8>(X); pstage<16>(X);   // idx 6,7,10,11
    dpp_bfly<0xB1>(X, s1);                          // idx 2
    dpp_bfly<0x4E>(X, s2);                          // idx 3
    swap_j2_l4(X); swap_j3_l5(X);                   // j2<-4, j3<-5
    pstage<8>(X); pstage<16>(X);                    // idx 4, 5

    // bias prefetch (store custody = EX1-R layout, g<8: coalesced 1KB/instr)
    float4 bv[8];
#pragma unroll
    for (int g = 0; g < 8; ++g)
        bv[g] = *(const float4*)(bias + b_r1 + GOFF4(g, 256, 512, 4096, 0));

    // EX3
    BAR();                                          // protect EX2 reads
    { const int Q = physf(b_w3); WRX(Q, 64, 128, 16, 32); }
    BAR();
    { const int Q = physf(b_r1); RDX(Q, 256, 512, 4096, 8192); }
    pstage<2>(X); pstage<4>(X); pstage<8>(X); pstage<16>(X);   // idx 8,9,12,13

    // ---------- epilogue: idx13 = j3 -> packs with bit4=0 (g<8) ----------
    {
        float* orow = out + (size_t)r * NRES;
        const float inv = 1.0f / (float)NH;
#pragma unroll
        for (int g = 0; g < 8; ++g) {
            const int a = b_r1 + GOFF4(g, 256, 512, 4096, 0);
            float4 o;
            o.x = erf_fast(fmaf(X[2*g].x,   inv, bv[g].x));
            o.y = erf_fast(fmaf(X[2*g].y,   inv, bv[g].y));
            o.z = erf_fast(fmaf(X[2*g+1].x, inv, bv[g].z));
            o.w = erf_fast(fmaf(X[2*g+1].y, inv, bv[g].w));
            *(float4*)(orow + a) = o;
        }
    }
}

extern "C" void kernel_launch(void* const* d_in, const int* in_sizes, int n_in,
                              void* d_out, int out_size, void* d_ws, size_t ws_size,
                              hipStream_t stream) {
    (void)in_sizes; (void)n_in; (void)out_size; (void)d_ws; (void)ws_size;
    const float* state  = (const float*)d_in[0];
    const float* inputs = (const float*)d_in[1];
    const float* bias   = (const float*)d_in[2];
    const float* diag   = (const float*)d_in[3];
    float* out = (float*)d_out;

    hipLaunchKernelGGL(st_kernel, dim3(BATCH), dim3(256), 0, stream,
                       state, inputs, bias, diag, out);
}